// Round 4
// baseline (1721.753 us; speedup 1.0000x reference)
//
#include <hip/hip_runtime.h>

#define S_LEN 2048
#define I_IN  32
#define H_DIM 64
#define O_DIM 32
#define NSEQ  256
#define NROWS (NSEQ * S_LEN)          // 524288
#define OBS_ELEMS (NROWS * O_DIM)     // 16777216
#define HID_ELEMS (NROWS * H_DIM)     // 33554432

// One wave (64 lanes) per sequence q. Lane g owns hidden unit g.
// W_ih row / W_hh row in VGPRs (fp32); h broadcast through LDS each step.
__global__ __launch_bounds__(64, 1) void rnn_scan_kernel(
    const float* __restrict__ x,
    const float* __restrict__ Wih,
    const float* __restrict__ bih,
    const float* __restrict__ Whh,
    const float* __restrict__ bhh,
    float* __restrict__ hidden,
    float* __restrict__ hlast)
{
    const int q = blockIdx.x;
    const int g = threadIdx.x;

    __shared__ float h_sh[H_DIM];

    float wih[I_IN];
#pragma unroll
    for (int i = 0; i < I_IN; ++i) wih[i] = Wih[g * I_IN + i];
    float whh[H_DIM];
#pragma unroll
    for (int h = 0; h < H_DIM; ++h) whh[h] = Whh[g * H_DIM + h];
    const float bias = bih[g] + bhh[g];

    h_sh[g] = 0.0f;
    __syncthreads();

    const float4* xrow = (const float4*)(x + (size_t)q * S_LEN * I_IN); // 8 float4/step
    float* hq = hidden + (size_t)q * S_LEN * H_DIM;

    float4 cur[8];
#pragma unroll
    for (int k = 0; k < 8; ++k) cur[k] = xrow[k];
    float hv = 0.0f;

    for (int t = 0; t < S_LEN; ++t) {
        const int tn = (t + 1 < S_LEN) ? (t + 1) : t;
        float4 nxt[8];
#pragma unroll
        for (int k = 0; k < 8; ++k) nxt[k] = xrow[tn * 8 + k];

        // input projection: pre[g] = sum_i Wih[g][i]*x[t][i] + b_ih[g] + b_hh[g]
        float p0 = bias, p1 = 0.0f, p2 = 0.0f, p3 = 0.0f;
#pragma unroll
        for (int k = 0; k < 8; ++k) {
            p0 = fmaf(wih[4 * k + 0], cur[k].x, p0);
            p1 = fmaf(wih[4 * k + 1], cur[k].y, p1);
            p2 = fmaf(wih[4 * k + 2], cur[k].z, p2);
            p3 = fmaf(wih[4 * k + 3], cur[k].w, p3);
        }

        // recurrent matvec: z[g] = sum_h Whh[g][h] * h_prev[h]
        float z0 = 0.0f, z1 = 0.0f, z2 = 0.0f, z3 = 0.0f;
#pragma unroll
        for (int h = 0; h < H_DIM; h += 4) {
            z0 = fmaf(whh[h + 0], h_sh[h + 0], z0);
            z1 = fmaf(whh[h + 1], h_sh[h + 1], z1);
            z2 = fmaf(whh[h + 2], h_sh[h + 2], z2);
            z3 = fmaf(whh[h + 3], h_sh[h + 3], z3);
        }
        const float z = ((p0 + p1) + (p2 + p3)) + ((z0 + z1) + (z2 + z3));

        // tanh(z) = 1 - 2/(exp(2z)+1): branchless, NaN-free for finite z
        const float e = __expf(2.0f * z);
        hv = 1.0f - 2.0f / (e + 1.0f);

        hq[t * H_DIM + g] = hv;

        __syncthreads();          // single wave: cheap
        h_sh[g] = hv;
        __syncthreads();

#pragma unroll
        for (int k = 0; k < 8; ++k) cur[k] = nxt[k];
    }

    hlast[q * H_DIM + g] = hv;
}

// obs[row][o] = sum_h hidden[row][h]*W_fc[o][h] + b_fc[o]
// 4096 blocks x 256 threads; 128 rows/block. h tile staged TRANSPOSED in LDS
// (hsh[h][r], row stride 132 keeps 16B alignment), W^T staged as wt[h][o].
// Thread (og,rg) computes 4 rows x 4 outs; inner loop = 2 ds_read_b128 + 16 fma.
__global__ __launch_bounds__(256) void obs_kernel(
    const float* __restrict__ hidden,
    const float* __restrict__ Wfc,
    const float* __restrict__ bfc,
    float* __restrict__ obs)
{
    __shared__ float hsh[H_DIM][132];   // [h][row], 33 KB
    __shared__ float wt[H_DIM][36];     // [h][o],   9 KB
    __shared__ float bsh[O_DIM];

    const int tid = threadIdx.x;
    const size_t rowbase = (size_t)blockIdx.x * 128;

    // stage hidden tile transposed: 2048 float4 loads (8 per thread), coalesced
    // R3 BUG WAS HERE: loop ran s<2 (only rows 0..31 staged) -> LDS garbage.
    const float4* hg = (const float4*)(hidden + rowbase * H_DIM);
#pragma unroll
    for (int s = 0; s < 8; ++s) {
        const int f = tid + 256 * s;     // 0..2047; 16 float4 per row, 128 rows
        const int r = f >> 4, h4 = f & 15;
        const float4 v = hg[f];
        hsh[h4 * 4 + 0][r] = v.x;
        hsh[h4 * 4 + 1][r] = v.y;
        hsh[h4 * 4 + 2][r] = v.z;
        hsh[h4 * 4 + 3][r] = v.w;
    }
    // stage W^T (2048 elems) and bias
#pragma unroll
    for (int s = 0; s < 8; ++s) {
        const int e = tid + 256 * s;     // e = o*64 + h
        wt[e & 63][e >> 6] = Wfc[e];
    }
    if (tid < O_DIM) bsh[tid] = bfc[tid];
    __syncthreads();

    const int rg = tid & 31, og = tid >> 5;
    const int r0 = rg * 4, o0 = og * 4;

    float acc[4][4];
#pragma unroll
    for (int j = 0; j < 4; ++j)
#pragma unroll
        for (int i = 0; i < 4; ++i) acc[j][i] = 0.0f;

#pragma unroll 8
    for (int h = 0; h < H_DIM; ++h) {
        const float4 hv = *(const float4*)&hsh[h][r0];  // rows r0..r0+3
        const float4 wv = *(const float4*)&wt[h][o0];   // outs o0..o0+3 (broadcast)
        const float hj[4] = {hv.x, hv.y, hv.z, hv.w};
        const float wi[4] = {wv.x, wv.y, wv.z, wv.w};
#pragma unroll
        for (int j = 0; j < 4; ++j)
#pragma unroll
            for (int i = 0; i < 4; ++i)
                acc[j][i] = fmaf(hj[j], wi[i], acc[j][i]);
    }

    const float4 bv = *(const float4*)&bsh[o0];
    const float bi[4] = {bv.x, bv.y, bv.z, bv.w};
#pragma unroll
    for (int j = 0; j < 4; ++j) {
        float4 ov;
        ov.x = acc[j][0] + bi[0];
        ov.y = acc[j][1] + bi[1];
        ov.z = acc[j][2] + bi[2];
        ov.w = acc[j][3] + bi[3];
        *(float4*)&obs[(rowbase + r0 + j) * O_DIM + o0] = ov;
    }
}

extern "C" void kernel_launch(void* const* d_in, const int* in_sizes, int n_in,
                              void* d_out, int out_size, void* d_ws, size_t ws_size,
                              hipStream_t stream)
{
    const float* x   = (const float*)d_in[0];
    const float* Wih = (const float*)d_in[1];
    const float* bih = (const float*)d_in[2];
    const float* Whh = (const float*)d_in[3];
    const float* bhh = (const float*)d_in[4];
    const float* Wfc = (const float*)d_in[5];
    const float* bfc = (const float*)d_in[6];

    float* out    = (float*)d_out;
    float* obs    = out;                         // [8,32,2048,32]
    float* hidden = out + (size_t)OBS_ELEMS;     // [8,32,2048,64]
    float* hlast  = hidden + (size_t)HID_ELEMS;  // [8,32,64]

    rnn_scan_kernel<<<NSEQ, 64, 0, stream>>>(x, Wih, bih, Whh, bhh, hidden, hlast);
    obs_kernel<<<NROWS / 128, 256, 0, stream>>>(hidden, Wfc, bfc, obs);
}